// Round 2
// baseline (236.991 us; speedup 1.0000x reference)
//
#include <hip/hip_runtime.h>
#include <hip/hip_bf16.h>
#include <stdint.h>

#define BM 128
#define BN 128
#define BK 64

typedef __attribute__((ext_vector_type(8))) short    bf16x8;  // 8×16-bit = 4 VGPR (MFMA A/B frag)
typedef __attribute__((ext_vector_type(8))) _Float16 f16x8;
typedef __attribute__((ext_vector_type(4))) float    f32x4;   // MFMA acc

typedef __attribute__((address_space(1))) void GV;            // global
typedef __attribute__((address_space(3))) void LV;            // LDS

__device__ __forceinline__ unsigned short f2bf(float f){
  union { float f; unsigned u; } x; x.f = f;
  unsigned r = x.u + 0x7fffu + ((x.u >> 16) & 1u);            // RNE
  return (unsigned short)(r >> 16);
}
__device__ __forceinline__ float bf2f(unsigned short h){
  union { unsigned u; float f; } x; x.u = ((unsigned)h) << 16; return x.f;
}
__device__ __forceinline__ unsigned short f2h(float f){
  union { _Float16 h; unsigned short u; } c; c.h = (_Float16)f; return c.u;  // RNE
}

// ---- shared GEMM skeleton: C[128x128] = A[128xK] * Bt[128xK]^T, 16-bit in, f32 acc ----
// LDS tile: [row][64 k] 16-bit, 128B rows, XOR-swizzled byte ^= (row&7)<<4.
// global_load_lds writes LINEAR dest; global source address is pre-swizzled (rule #21).

__device__ __forceinline__ void stage_tile(const unsigned short* __restrict__ src, int ld,
                                           unsigned short* lds, int tid){
  #pragma unroll
  for (int t = 0; t < 4; ++t){
    int idx = t*256 + tid;              // 0..1023, 16B each = 16KB tile
    int row = idx >> 3;                 // 0..127
    int kc  = (idx & 7) ^ (row & 7);    // pre-swizzled k-chunk (8 elems)
    const unsigned short* g = src + (size_t)row*ld + kc*8;
    __builtin_amdgcn_global_load_lds((GV*)g, (LV*)(lds + idx*8), 16, 0, 0);
  }
}

__device__ __forceinline__ bf16x8 frag_ld(const unsigned short* lds, int r, int k){
  int byte = ((r << 7) + (k << 1)) ^ ((r & 7) << 4);          // swizzled read
  return *(const bf16x8*)((const char*)lds + byte);
}

template<bool F16>
__device__ __forceinline__ void gemm_core(const unsigned short* __restrict__ At,
                                          const unsigned short* __restrict__ Bt,
                                          int lda, int ldb, int nkt,
                                          unsigned short* lsA, unsigned short* lsB,
                                          f32x4 (&acc)[4][4]){
  const int tid  = threadIdx.x;
  const int lane = tid & 63;
  const int wr = ((tid >> 7) & 1) << 6;   // wave (2x2): row offset
  const int wc = ((tid >> 6) & 1) << 6;   // col offset
  const int l15 = lane & 15, lg = lane >> 4;

  for (int kt = 0; kt < nkt; ++kt){
    stage_tile(At + (size_t)kt*BK, lda, lsA, tid);
    stage_tile(Bt + (size_t)kt*BK, ldb, lsB, tid);
    __syncthreads();
    #pragma unroll
    for (int kk = 0; kk < 2; ++kk){
      bf16x8 af[4], bfr[4];
      #pragma unroll
      for (int mf = 0; mf < 4; ++mf) af[mf]  = frag_ld(lsA, wr + mf*16 + l15, kk*32 + lg*8);
      #pragma unroll
      for (int nf = 0; nf < 4; ++nf) bfr[nf] = frag_ld(lsB, wc + nf*16 + l15, kk*32 + lg*8);
      #pragma unroll
      for (int mf = 0; mf < 4; ++mf)
        #pragma unroll
        for (int nf = 0; nf < 4; ++nf){
          if constexpr (F16)
            acc[mf][nf] = __builtin_amdgcn_mfma_f32_16x16x32_f16(
                __builtin_bit_cast(f16x8, af[mf]), __builtin_bit_cast(f16x8, bfr[nf]),
                acc[mf][nf], 0, 0, 0);
          else
            acc[mf][nf] = __builtin_amdgcn_mfma_f32_16x16x32_bf16(af[mf], bfr[nf], acc[mf][nf], 0, 0, 0);
        }
    }
    __syncthreads();
  }
}

#define ZERO_ACC(acc) { _Pragma("unroll") for (int i_=0;i_<4;++i_) _Pragma("unroll") for (int j_=0;j_<4;++j_) acc[i_][j_] = (f32x4){0.f,0.f,0.f,0.f}; }

// ---- converts (fp32 -> fp16) ----
__global__ __launch_bounds__(256) void k_cvt_x(const float* __restrict__ x,
                                               unsigned short* __restrict__ xh, int n4){
  int i = blockIdx.x*blockDim.x + threadIdx.x;
  int stride = gridDim.x*blockDim.x;
  for (; i < n4; i += stride){
    float4 v = ((const float4*)x)[i];
    ushort4 o; o.x = f2h(v.x); o.y = f2h(v.y); o.z = f2h(v.z); o.w = f2h(v.w);
    ((ushort4*)xh)[i] = o;
  }
}

// Wt[n][k] (n: 0-127 Q, 128-255 K, 256-1279 V), fp16, k = 0..1023
__global__ __launch_bounds__(256) void k_cvt_wt(const float* __restrict__ Wq, const float* __restrict__ Wk,
                                                const float* __restrict__ Wv, unsigned short* __restrict__ Wt){
  int n = blockIdx.x*32 + threadIdx.x;
  int k = blockIdx.y*8  + threadIdx.y;
  float v;
  if (n < 128)      v = Wq[(size_t)k*128  + n];
  else if (n < 256) v = Wk[(size_t)k*128  + (n-128)];
  else              v = Wv[(size_t)k*1024 + (n-256)];
  Wt[(size_t)n*1024 + k] = f2h(v);
}

// ---- fused QKV projection (fp16 GEMM); Q,K stored fp16; V stored bf16 transposed Vt[b][j][t] ----
__global__ __launch_bounds__(256) void k_proj(const unsigned short* __restrict__ xh,
                                              const unsigned short* __restrict__ Wt,
                                              const float* __restrict__ bq, const float* __restrict__ bk,
                                              const float* __restrict__ bv,
                                              unsigned short* __restrict__ Qh, unsigned short* __restrict__ Kh,
                                              unsigned short* __restrict__ Vt){
  __shared__ unsigned short lsA[BM*BK], lsB[BN*BK];
  const int m0 = blockIdx.x * BM;
  const int n0 = blockIdx.y * BN;          // 0..1279 in steps of 128
  f32x4 acc[4][4]; ZERO_ACC(acc);
  gemm_core<true>(xh + (size_t)m0*1024, Wt + (size_t)n0*1024, 1024, 1024, 16, lsA, lsB, acc);

  const int tid = threadIdx.x, lane = tid & 63;
  const int wr = ((tid >> 7) & 1) << 6;
  const int wc = ((tid >> 6) & 1) << 6;
  const int l15 = lane & 15, lg = lane >> 4;

  if (n0 < 256){                            // Q or K block -> fp16 row-major
    unsigned short* T   = (n0 == 0) ? Qh : Kh;
    const float*  bias  = (n0 == 0) ? bq : bk;
    #pragma unroll
    for (int mf = 0; mf < 4; ++mf){
      #pragma unroll
      for (int nf = 0; nf < 4; ++nf){
        int c = wc + nf*16 + l15;           // 0..127
        float bi = bias[c];
        #pragma unroll
        for (int r = 0; r < 4; ++r){
          int gr = m0 + wr + mf*16 + lg*4 + r;
          T[(size_t)gr*128 + c] = f2h(acc[mf][nf][r] + bi);
        }
      }
    }
  } else {                                  // V block -> bf16 transposed store
    int jb = n0 - 256;
    #pragma unroll
    for (int mf = 0; mf < 4; ++mf){
      int gr0 = m0 + wr + mf*16 + lg*4;     // 4 consecutive rows (= seq positions)
      int b   = gr0 >> 11;
      int t0  = gr0 & 2047;
      #pragma unroll
      for (int nf = 0; nf < 4; ++nf){
        int j = jb + wc + nf*16 + l15;
        float bi = bv[j];
        ushort4 pk;
        pk.x = f2bf(acc[mf][nf][0] + bi);
        pk.y = f2bf(acc[mf][nf][1] + bi);
        pk.z = f2bf(acc[mf][nf][2] + bi);
        pk.w = f2bf(acc[mf][nf][3] + bi);
        *(ushort4*)(Vt + ((size_t)b*1024 + j)*2048 + t0) = pk;
      }
    }
  }
}

// ---- scores: P_unnorm = exp(Q K^T) bf16, + per-row sum via atomics (no max needed: |s| << 88) ----
__global__ __launch_bounds__(256) void k_scores(const unsigned short* __restrict__ Qh,
                                                const unsigned short* __restrict__ Kh,
                                                unsigned short* __restrict__ P, float* __restrict__ lsum){
  __shared__ unsigned short lsA[BM*BK], lsB[BN*BK];
  const int s0 = blockIdx.x * BM;
  const int t0 = blockIdx.y * BN;
  const int b  = blockIdx.z;
  f32x4 acc[4][4]; ZERO_ACC(acc);
  gemm_core<true>(Qh + ((size_t)b*2048 + s0)*128, Kh + ((size_t)b*2048 + t0)*128, 128, 128, 2, lsA, lsB, acc);

  unsigned short* Pb = P + (size_t)b*2048*2048;
  float* lb = lsum + b*2048;
  const int tid = threadIdx.x, lane = tid & 63;
  const int wr = ((tid >> 7) & 1) << 6;
  const int wc = ((tid >> 6) & 1) << 6;
  const int l15 = lane & 15, lg = lane >> 4;

  #pragma unroll
  for (int mf = 0; mf < 4; ++mf){
    #pragma unroll
    for (int r = 0; r < 4; ++r){
      int sr = s0 + wr + mf*16 + lg*4 + r;
      float rsum = 0.f;
      #pragma unroll
      for (int nf = 0; nf < 4; ++nf){
        float e = __expf(acc[mf][nf][r]);
        unsigned short h = f2bf(e);
        int tc = t0 + wc + nf*16 + l15;
        Pb[(size_t)sr*2048 + tc] = h;
        rsum += bf2f(h);                    // sum the ROUNDED values (common-mode cancels)
      }
      #pragma unroll
      for (int d = 1; d < 16; d <<= 1) rsum += __shfl_xor(rsum, d);
      if (l15 == 0) atomicAdd(&lb[sr], rsum);
    }
  }
}

// ---- PV: out = tanh( (P_unnorm @ V) / l )  (bf16 GEMM) ----
__global__ __launch_bounds__(256) void k_pv(const unsigned short* __restrict__ P,
                                            const unsigned short* __restrict__ Vt,
                                            const float* __restrict__ lsum, float* __restrict__ out){
  __shared__ unsigned short lsA[BM*BK], lsB[BN*BK];
  const int s0 = blockIdx.x * BM;
  const int j0 = blockIdx.y * BN;
  const int b  = blockIdx.z;
  f32x4 acc[4][4]; ZERO_ACC(acc);
  gemm_core<false>(P  + ((size_t)b*2048 + s0)*2048,
                   Vt + ((size_t)b*1024 + j0)*2048, 2048, 2048, 32, lsA, lsB, acc);

  const float* lb = lsum + b*2048;
  float* ob = out + (size_t)b*2048*1024;
  const int tid = threadIdx.x, lane = tid & 63;
  const int wr = ((tid >> 7) & 1) << 6;
  const int wc = ((tid >> 6) & 1) << 6;
  const int l15 = lane & 15, lg = lane >> 4;

  #pragma unroll
  for (int mf = 0; mf < 4; ++mf){
    #pragma unroll
    for (int r = 0; r < 4; ++r){
      int sr = s0 + wr + mf*16 + lg*4 + r;
      float rl = 1.0f / lb[sr];
      #pragma unroll
      for (int nf = 0; nf < 4; ++nf){
        int jc = j0 + wc + nf*16 + l15;
        float v = acc[mf][nf][r] * rl;
        ob[(size_t)sr*1024 + jc] = 1.0f - 2.0f/(1.0f + __expf(2.0f*v));   // tanh, saturation-safe
      }
    }
  }
}

extern "C" void kernel_launch(void* const* d_in, const int* in_sizes, int n_in,
                              void* d_out, int out_size, void* d_ws, size_t ws_size,
                              hipStream_t stream){
  const float* x  = (const float*)d_in[0];
  const float* Wq = (const float*)d_in[1];
  const float* bq = (const float*)d_in[2];
  const float* Wk = (const float*)d_in[3];
  const float* bk = (const float*)d_in[4];
  const float* Wv = (const float*)d_in[5];
  const float* bv = (const float*)d_in[6];
  float* out = (float*)d_out;

  char* ws = (char*)d_ws;
  const size_t MB = 1024*1024;
  unsigned short* Wt   = (unsigned short*)(ws);            // 2.62MB ([1280][1024] fp16)
  unsigned short* Qh   = (unsigned short*)(ws + 4*MB);     // 4MB   ([16384][128] fp16)
  unsigned short* Kh   = (unsigned short*)(ws + 8*MB);     // 4MB
  unsigned short* Vt   = (unsigned short*)(ws + 12*MB);    // 32MB  ([8][1024][2048] bf16)
  unsigned short* P    = (unsigned short*)(ws + 44*MB);    // 64MB  ([8][2048][2048] bf16)
  float*          lsum = (float*)(ws + 108*MB);            // 64KB  ([8][2048] f32)
  unsigned short* xh   = (unsigned short*)d_out;           // scratch: x in fp16 (32MB of the 64MB out buf)

  hipMemsetAsync(lsum, 0, 16384*sizeof(float), stream);
  k_cvt_x  <<<2048, 256, 0, stream>>>(x, xh, 16384*1024/4);
  k_cvt_wt <<<dim3(40,128), dim3(32,8), 0, stream>>>(Wq, Wk, Wv, Wt);
  k_proj   <<<dim3(128,10), 256, 0, stream>>>(xh, Wt, bq, bk, bv, Qh, Kh, Vt);
  k_scores <<<dim3(16,16,8), 256, 0, stream>>>(Qh, Kh, P, lsum);
  k_pv     <<<dim3(16,8,8),  256, 0, stream>>>(P, Vt, lsum, out);
}

// Round 3
// 212.956 us; speedup vs baseline: 1.1129x; 1.1129x over previous
//
#include <hip/hip_runtime.h>
#include <hip/hip_bf16.h>
#include <stdint.h>

#define BM 128
#define BN 128
#define BK 64

typedef __attribute__((ext_vector_type(8))) short    bf16x8;  // 8×16-bit = 4 VGPR (MFMA A/B frag)
typedef __attribute__((ext_vector_type(8))) _Float16 f16x8;
typedef __attribute__((ext_vector_type(4))) float    f32x4;   // MFMA acc

typedef __attribute__((address_space(1))) void GV;            // global
typedef __attribute__((address_space(3))) void LV;            // LDS

__device__ __forceinline__ unsigned short f2bf(float f){
  union { float f; unsigned u; } x; x.f = f;
  unsigned r = x.u + 0x7fffu + ((x.u >> 16) & 1u);            // RNE
  return (unsigned short)(r >> 16);
}
__device__ __forceinline__ float bf2f(unsigned short h){
  union { unsigned u; float f; } x; x.u = ((unsigned)h) << 16; return x.f;
}
__device__ __forceinline__ unsigned short f2h(float f){
  union { _Float16 h; unsigned short u; } c; c.h = (_Float16)f; return c.u;  // RNE
}

// swizzled LDS frag read: row-major [R][64] 16-bit tile, 128B rows, byte ^= (row&7)<<4
__device__ __forceinline__ bf16x8 frag_ld(const unsigned short* lds, int r, int k){
  int byte = ((r << 7) + (k << 1)) ^ ((r & 7) << 4);
  return *(const bf16x8*)((const char*)lds + byte);
}

// ================= old 128x128 2-phase core (kept for proj/scores; verified) =================
__device__ __forceinline__ void stage_tile(const unsigned short* __restrict__ src, int ld,
                                           unsigned short* lds, int tid){
  #pragma unroll
  for (int t = 0; t < 4; ++t){
    int idx = t*256 + tid;              // 0..1023, 16B each = 16KB tile
    int row = idx >> 3;                 // 0..127
    int kc  = (idx & 7) ^ (row & 7);    // pre-swizzled k-chunk (8 elems)
    const unsigned short* g = src + (size_t)row*ld + kc*8;
    __builtin_amdgcn_global_load_lds((GV*)g, (LV*)(lds + idx*8), 16, 0, 0);
  }
}

template<bool F16>
__device__ __forceinline__ void gemm_core(const unsigned short* __restrict__ At,
                                          const unsigned short* __restrict__ Bt,
                                          int lda, int ldb, int nkt,
                                          unsigned short* lsA, unsigned short* lsB,
                                          f32x4 (&acc)[4][4]){
  const int tid  = threadIdx.x;
  const int lane = tid & 63;
  const int wr = ((tid >> 7) & 1) << 6;
  const int wc = ((tid >> 6) & 1) << 6;
  const int l15 = lane & 15, lg = lane >> 4;

  for (int kt = 0; kt < nkt; ++kt){
    stage_tile(At + (size_t)kt*BK, lda, lsA, tid);
    stage_tile(Bt + (size_t)kt*BK, ldb, lsB, tid);
    __syncthreads();
    #pragma unroll
    for (int kk = 0; kk < 2; ++kk){
      bf16x8 af[4], bfr[4];
      #pragma unroll
      for (int mf = 0; mf < 4; ++mf) af[mf]  = frag_ld(lsA, wr + mf*16 + l15, kk*32 + lg*8);
      #pragma unroll
      for (int nf = 0; nf < 4; ++nf) bfr[nf] = frag_ld(lsB, wc + nf*16 + l15, kk*32 + lg*8);
      #pragma unroll
      for (int mf = 0; mf < 4; ++mf)
        #pragma unroll
        for (int nf = 0; nf < 4; ++nf){
          if constexpr (F16)
            acc[mf][nf] = __builtin_amdgcn_mfma_f32_16x16x32_f16(
                __builtin_bit_cast(f16x8, af[mf]), __builtin_bit_cast(f16x8, bfr[nf]),
                acc[mf][nf], 0, 0, 0);
          else
            acc[mf][nf] = __builtin_amdgcn_mfma_f32_16x16x32_bf16(af[mf], bfr[nf], acc[mf][nf], 0, 0, 0);
        }
    }
    __syncthreads();
  }
}

#define ZERO_ACC(acc) { _Pragma("unroll") for (int i_=0;i_<4;++i_) _Pragma("unroll") for (int j_=0;j_<4;++j_) acc[i_][j_] = (f32x4){0.f,0.f,0.f,0.f}; }

// ================= converts =================
__global__ __launch_bounds__(256) void k_cvt_x(const float* __restrict__ x,
                                               unsigned short* __restrict__ xh, int n4){
  int i = blockIdx.x*blockDim.x + threadIdx.x;
  int stride = gridDim.x*blockDim.x;
  for (; i < n4; i += stride){
    float4 v = ((const float4*)x)[i];
    ushort4 o; o.x = f2h(v.x); o.y = f2h(v.y); o.z = f2h(v.z); o.w = f2h(v.w);
    ((ushort4*)xh)[i] = o;
  }
}

__global__ __launch_bounds__(256) void k_cvt_wt(const float* __restrict__ Wq, const float* __restrict__ Wk,
                                                const float* __restrict__ Wv, unsigned short* __restrict__ Wt){
  int n = blockIdx.x*32 + threadIdx.x;
  int k = blockIdx.y*8  + threadIdx.y;
  float v;
  if (n < 128)      v = Wq[(size_t)k*128  + n];
  else if (n < 256) v = Wk[(size_t)k*128  + (n-128)];
  else              v = Wv[(size_t)k*1024 + (n-256)];
  Wt[(size_t)n*1024 + k] = f2h(v);
}

// ================= QKV projection (fp16 GEMM, 128² core) =================
__global__ __launch_bounds__(256) void k_proj(const unsigned short* __restrict__ xh,
                                              const unsigned short* __restrict__ Wt,
                                              const float* __restrict__ bq, const float* __restrict__ bk,
                                              const float* __restrict__ bv,
                                              unsigned short* __restrict__ Qh, unsigned short* __restrict__ Kh,
                                              unsigned short* __restrict__ Vt){
  __shared__ unsigned short lsA[BM*BK], lsB[BN*BK];
  const int m0 = blockIdx.x * BM;
  const int n0 = blockIdx.y * BN;
  f32x4 acc[4][4]; ZERO_ACC(acc);
  gemm_core<true>(xh + (size_t)m0*1024, Wt + (size_t)n0*1024, 1024, 1024, 16, lsA, lsB, acc);

  const int tid = threadIdx.x, lane = tid & 63;
  const int wr = ((tid >> 7) & 1) << 6;
  const int wc = ((tid >> 6) & 1) << 6;
  const int l15 = lane & 15, lg = lane >> 4;

  if (n0 < 256){
    unsigned short* T   = (n0 == 0) ? Qh : Kh;
    const float*  bias  = (n0 == 0) ? bq : bk;
    #pragma unroll
    for (int mf = 0; mf < 4; ++mf){
      #pragma unroll
      for (int nf = 0; nf < 4; ++nf){
        int c = wc + nf*16 + l15;
        float bi = bias[c];
        #pragma unroll
        for (int r = 0; r < 4; ++r){
          int gr = m0 + wr + mf*16 + lg*4 + r;
          T[(size_t)gr*128 + c] = f2h(acc[mf][nf][r] + bi);
        }
      }
    }
  } else {
    int jb = n0 - 256;
    #pragma unroll
    for (int mf = 0; mf < 4; ++mf){
      int gr0 = m0 + wr + mf*16 + lg*4;
      int b   = gr0 >> 11;
      int t0  = gr0 & 2047;
      #pragma unroll
      for (int nf = 0; nf < 4; ++nf){
        int j = jb + wc + nf*16 + l15;
        float bi = bv[j];
        ushort4 pk;
        pk.x = f2bf(acc[mf][nf][0] + bi);
        pk.y = f2bf(acc[mf][nf][1] + bi);
        pk.z = f2bf(acc[mf][nf][2] + bi);
        pk.w = f2bf(acc[mf][nf][3] + bi);
        *(ushort4*)(Vt + ((size_t)b*1024 + j)*2048 + t0) = pk;
      }
    }
  }
}

// ================= scores: P = exp(QK^T) bf16 + row-sum atomics (128² core) =================
__global__ __launch_bounds__(256) void k_scores(const unsigned short* __restrict__ Qh,
                                                const unsigned short* __restrict__ Kh,
                                                unsigned short* __restrict__ P, float* __restrict__ lsum){
  __shared__ unsigned short lsA[BM*BK], lsB[BN*BK];
  const int s0 = blockIdx.x * BM;
  const int t0 = blockIdx.y * BN;
  const int b  = blockIdx.z;
  f32x4 acc[4][4]; ZERO_ACC(acc);
  gemm_core<true>(Qh + ((size_t)b*2048 + s0)*128, Kh + ((size_t)b*2048 + t0)*128, 128, 128, 2, lsA, lsB, acc);

  unsigned short* Pb = P + (size_t)b*2048*2048;
  float* lb = lsum + b*2048;
  const int tid = threadIdx.x, lane = tid & 63;
  const int wr = ((tid >> 7) & 1) << 6;
  const int wc = ((tid >> 6) & 1) << 6;
  const int l15 = lane & 15, lg = lane >> 4;

  #pragma unroll
  for (int mf = 0; mf < 4; ++mf){
    #pragma unroll
    for (int r = 0; r < 4; ++r){
      int sr = s0 + wr + mf*16 + lg*4 + r;
      float rsum = 0.f;
      #pragma unroll
      for (int nf = 0; nf < 4; ++nf){
        float e = __expf(acc[mf][nf][r]);
        unsigned short h = f2bf(e);
        int tc = t0 + wc + nf*16 + l15;
        Pb[(size_t)sr*2048 + tc] = h;
        rsum += bf2f(h);
      }
      #pragma unroll
      for (int d = 1; d < 16; d <<= 1) rsum += __shfl_xor(rsum, d);
      if (l15 == 0) atomicAdd(&lb[sr], rsum);
    }
  }
}

// ================= PV: 256² 8-wave, 4-phase/K-tile, counted-vmcnt schedule =================
// LDS: A[2][256][64] + B[2][256][64] bf16 = 128 KiB dynamic. Swizzle byte ^= (row&7)<<4.
// Stage granularity: row-half (128 rows x 64 cols = 16KB = 2 global_load_lds/thread),
// required by global_load_lds' linear-dest constraint.
// Schedule per K-tile t (buffers cur=t&1): P1 reads kk0/mf0-3 + B kk0, stages A-h0(t+1)->oth;
// P2 reads kk0/mf4-7, stages A-h1(t+1)->oth; P3 reads kk1 (+B kk1); P4 reads kk1/mf4-7,
// stages B-h0,h1(t+2)->cur, then vmcnt(4): per-wave FIFO leaves exactly B(t+2)'s 4 loads
// outstanding while certifying all of tile t+1 landed. Hazard proof: region staged in phase p
// was fully consumed (all waves, lgkmcnt(0)-complete) before phase p-1's end barrier.

#define SBAR() { __builtin_amdgcn_sched_barrier(0); __builtin_amdgcn_s_barrier(); __builtin_amdgcn_sched_barrier(0); }
#define LGKM0() { asm volatile("s_waitcnt lgkmcnt(0)" ::: "memory"); __builtin_amdgcn_sched_barrier(0); }

__device__ __forceinline__ void stage_rows(const unsigned short* __restrict__ src, int ld,
                                           unsigned short* lds, int row0, int tid){
  #pragma unroll
  for (int q = 0; q < 2; ++q){
    int i  = q*512 + tid;               // 0..1023
    int lr = i >> 3;                    // 0..127
    int r  = row0 + lr;
    int kc = (i & 7) ^ (r & 7);         // pre-swizzled source (LDS dest stays linear)
    __builtin_amdgcn_global_load_lds((GV*)(src + (size_t)r*ld + kc*8),
                                     (LV*)(lds + (size_t)row0*64 + i*8), 16, 0, 0);
  }
}

__global__ __launch_bounds__(512, 2) void k_pv8(const unsigned short* __restrict__ P,
                                                const unsigned short* __restrict__ Vt,
                                                const float* __restrict__ lsum,
                                                float* __restrict__ out){
  extern __shared__ unsigned short sm[];   // 65536 ushort = 128KB

  const int tid  = threadIdx.x;
  const int lane = tid & 63, l15 = lane & 15, lg = lane >> 4;
  const int wid  = tid >> 6;
  const int wrow0 = (wid >> 2) << 7;       // 0 / 128
  const int wcol0 = (wid & 3) << 6;        // 0 / 64 / 128 / 192

  const int bid = blockIdx.x;              // 256 blocks = 1/CU; batch = bid&7 -> per-XCD L2 locality
  const int b   = bid & 7;
  const int r2  = bid >> 3;
  const int s0  = (r2 >> 2) << 8;
  const int j0  = (r2 & 3) << 8;

  const unsigned short* Abase = P  + ((size_t)b*2048 + s0)*2048;   // 256 rows, ld 2048
  const unsigned short* Bbase = Vt + ((size_t)b*1024 + j0)*2048;
  const int nkt = 32;

  f32x4 acc[8][4];
  #pragma unroll
  for (int i = 0; i < 8; ++i)
    #pragma unroll
    for (int j = 0; j < 4; ++j) acc[i][j] = (f32x4){0.f,0.f,0.f,0.f};

  // prologue: A(0) h0,h1; B(0) h0,h1; B(1) h0,h1  (12 loads/wave)
  {
    unsigned short* A0 = sm;             unsigned short* B0 = sm + 32768;
    unsigned short* B1 = sm + 49152;
    stage_rows(Abase,      2048, A0, 0,   tid);
    stage_rows(Abase,      2048, A0, 128, tid);
    stage_rows(Bbase,      2048, B0, 0,   tid);
    stage_rows(Bbase,      2048, B0, 128, tid);
    stage_rows(Bbase + 64, 2048, B1, 0,   tid);
    stage_rows(Bbase + 64, 2048, B1, 128, tid);
  }
  asm volatile("s_waitcnt vmcnt(4)" ::: "memory");   // tile0's 8 loads landed
  __builtin_amdgcn_sched_barrier(0);
  SBAR();

  for (int t = 0; t < nkt; ++t){
    unsigned short* A  = sm + ((t & 1) << 14);
    unsigned short* B  = sm + 32768 + ((t & 1) << 14);
    unsigned short* An = sm + (((t + 1) & 1) << 14);
    bf16x8 af[4], bfr[4];

    // ---- P1: kk0, mf0-3; stage A-h0(t+1)
    #pragma unroll
    for (int mf = 0; mf < 4; ++mf) af[mf]  = frag_ld(A, wrow0 + mf*16 + l15, lg*8);
    #pragma unroll
    for (int nf = 0; nf < 4; ++nf) bfr[nf] = frag_ld(B, wcol0 + nf*16 + l15, lg*8);
    if (t + 1 < nkt) stage_rows(Abase + (size_t)(t+1)*64, 2048, An, 0, tid);
    SBAR(); LGKM0();
    __builtin_amdgcn_s_setprio(1);
    #pragma unroll
    for (int mf = 0; mf < 4; ++mf)
      #pragma unroll
      for (int nf = 0; nf < 4; ++nf)
        acc[mf][nf] = __builtin_amdgcn_mfma_f32_16x16x32_bf16(af[mf], bfr[nf], acc[mf][nf], 0, 0, 0);
    __builtin_amdgcn_s_setprio(0);
    SBAR();

    // ---- P2: kk0, mf4-7 (reuse B regs); stage A-h1(t+1)
    #pragma unroll
    for (int mf = 0; mf < 4; ++mf) af[mf] = frag_ld(A, wrow0 + (mf+4)*16 + l15, lg*8);
    if (t + 1 < nkt) stage_rows(Abase + (size_t)(t+1)*64, 2048, An, 128, tid);
    SBAR(); LGKM0();
    __builtin_amdgcn_s_setprio(1);
    #pragma unroll
    for (int mf = 0; mf < 4; ++mf)
      #pragma unroll
      for (int nf = 0; nf < 4; ++nf)
        acc[mf+4][nf] = __builtin_amdgcn_mfma_f32_16x16x32_bf16(af[mf], bfr[nf], acc[mf+4][nf], 0, 0, 0);
    __builtin_amdgcn_s_setprio(0);
    SBAR();

    // ---- P3: kk1, mf0-3 (+ B kk1); no stage
    #pragma unroll
    for (int mf = 0; mf < 4; ++mf) af[mf]  = frag_ld(A, wrow0 + mf*16 + l15, 32 + lg*8);
    #pragma unroll
    for (int nf = 0; nf < 4; ++nf) bfr[nf] = frag_ld(B, wcol0 + nf*16 + l15, 32 + lg*8);
    SBAR(); LGKM0();
    __builtin_amdgcn_s_setprio(1);
    #pragma unroll
    for (int mf = 0; mf < 4; ++mf)
      #pragma unroll
      for (int nf = 0; nf < 4; ++nf)
        acc[mf][nf] = __builtin_amdgcn_mfma_f32_16x16x32_bf16(af[mf], bfr[nf], acc[mf][nf], 0, 0, 0);
    __builtin_amdgcn_s_setprio(0);
    SBAR();

    // ---- P4: kk1, mf4-7; stage B h0,h1(t+2) -> cur; counted vmcnt
    #pragma unroll
    for (int mf = 0; mf < 4; ++mf) af[mf] = frag_ld(A, wrow0 + (mf+4)*16 + l15, 32 + lg*8);
    if (t + 2 < nkt){
      stage_rows(Bbase + (size_t)(t+2)*64, 2048, B, 0,   tid);
      stage_rows(Bbase + (size_t)(t+2)*64, 2048, B, 128, tid);
      asm volatile("s_waitcnt vmcnt(4)" ::: "memory");  // tile t+1 fully landed; B(t+2) in flight
      __builtin_amdgcn_sched_barrier(0);
    } else if (t + 1 < nkt){
      asm volatile("s_waitcnt vmcnt(0)" ::: "memory");  // tail: drain A(t+1)
      __builtin_amdgcn_sched_barrier(0);
    }
    SBAR(); LGKM0();
    __builtin_amdgcn_s_setprio(1);
    #pragma unroll
    for (int mf = 0; mf < 4; ++mf)
      #pragma unroll
      for (int nf = 0; nf < 4; ++nf)
        acc[mf+4][nf] = __builtin_amdgcn_mfma_f32_16x16x32_bf16(af[mf], bfr[nf], acc[mf+4][nf], 0, 0, 0);
    __builtin_amdgcn_s_setprio(0);
    SBAR();
  }

  // epilogue: /l, tanh, store fp32
  const float* lb = lsum + b*2048;
  float* ob = out + (size_t)b*2048*1024;
  #pragma unroll
  for (int mf = 0; mf < 8; ++mf){
    #pragma unroll
    for (int r = 0; r < 4; ++r){
      int srl = wrow0 + mf*16 + lg*4 + r;
      int sr  = s0 + srl;
      float rl = 1.0f / lb[sr];
      #pragma unroll
      for (int nf = 0; nf < 4; ++nf){
        int jc = j0 + wcol0 + nf*16 + l15;
        float v = acc[mf][nf][r] * rl;
        ob[(size_t)sr*1024 + jc] = 1.0f - 2.0f/(1.0f + __expf(2.0f*v));
      }
    }
  }
}

extern "C" void kernel_launch(void* const* d_in, const int* in_sizes, int n_in,
                              void* d_out, int out_size, void* d_ws, size_t ws_size,
                              hipStream_t stream){
  const float* x  = (const float*)d_in[0];
  const float* Wq = (const float*)d_in[1];
  const float* bq = (const float*)d_in[2];
  const float* Wk = (const float*)d_in[3];
  const float* bk = (const float*)d_in[4];
  const float* Wv = (const float*)d_in[5];
  const float* bv = (const float*)d_in[6];
  float* out = (float*)d_out;

  char* ws = (char*)d_ws;
  const size_t MB = 1024*1024;
  unsigned short* Wt   = (unsigned short*)(ws);            // [1280][1024] fp16
  unsigned short* Qh   = (unsigned short*)(ws + 4*MB);     // [16384][128] fp16
  unsigned short* Kh   = (unsigned short*)(ws + 8*MB);
  unsigned short* Vt   = (unsigned short*)(ws + 12*MB);    // [8][1024][2048] bf16
  unsigned short* P    = (unsigned short*)(ws + 44*MB);    // [8][2048][2048] bf16
  float*          lsum = (float*)(ws + 108*MB);            // [8][2048] f32
  unsigned short* xh   = (unsigned short*)d_out;           // scratch: x fp16 in out buf

  hipMemsetAsync(lsum, 0, 16384*sizeof(float), stream);
  k_cvt_x  <<<2048, 256, 0, stream>>>(x, xh, 16384*1024/4);
  k_cvt_wt <<<dim3(40,128), dim3(32,8), 0, stream>>>(Wq, Wk, Wv, Wt);
  k_proj   <<<dim3(128,10), 256, 0, stream>>>(xh, Wt, bq, bk, bv, Qh, Kh, Vt);
  k_scores <<<dim3(16,16,8), 256, 0, stream>>>(Qh, Kh, P, lsum);
  k_pv8    <<<256, 512, 131072, stream>>>(P, Vt, lsum, out);
}